// Round 21
// baseline (284.301 us; speedup 1.0000x reference)
//
#include <hip/hip_runtime.h>

#define NB 256   // edge chunks for hist/scatter passes
#define ND 256   // digit buckets

typedef _Float16 f16x8 __attribute__((ext_vector_type(8)));
typedef _Float16 f16x4 __attribute__((ext_vector_type(4)));
typedef float f32x4 __attribute__((ext_vector_type(4)));

__device__ inline void wfrag128(const float* wl, const float* wr, f16x8* out, int idx) {
    int lane_i = idx & 63, t = idx >> 6;
    int col = (t & 3) * 16 + (lane_i & 15);
    int krow = (t >> 2) * 32 + ((lane_i >> 4) << 3);
    f16x8 v;
    #pragma unroll
    for (int j = 0; j < 8; ++j) {
        int k = krow + j;
        const float* W = (k < 64) ? (wl + (size_t)k * 64) : (wr + (size_t)(k - 64) * 64);
        v[j] = (_Float16)W[col];
    }
    out[t * 64 + lane_i] = v;
}
__device__ inline void wfrag64(const float* wd, f16x8* out, int idx) {
    int lane_i = idx & 63, t = idx >> 6;
    int col = (t & 3) * 16 + (lane_i & 15);
    int krow = (t >> 2) * 32 + ((lane_i >> 4) << 3);
    f16x8 v;
    #pragma unroll
    for (int j = 0; j < 8; ++j)
        v[j] = (_Float16)wd[(size_t)(krow + j) * 64 + col];
    out[t * 64 + lane_i] = v;
}

// ---------------- fused start-of-frame: histograms + all weight prep + user16 convert ----------------
__global__ __launch_bounds__(1024) void k_init(const int* __restrict__ src, const int* __restrict__ dst,
                                               int* __restrict__ hist_u, int* __restrict__ hist_m,
                                               int E, int chunk,
                                               const float* __restrict__ c1mwl, const float* __restrict__ c1mwr,
                                               const float* __restrict__ c1uwl, const float* __restrict__ c1uwr,
                                               const float* __restrict__ c2mwl, const float* __restrict__ c2mwr,
                                               const float* __restrict__ c2uwl, const float* __restrict__ c2uwr,
                                               const float* __restrict__ decw1, const float* __restrict__ projw,
                                               const float* __restrict__ uemb,
                                               f16x8* __restrict__ wtab, _Float16* __restrict__ user16, int un4) {
    int b = blockIdx.x, tid = threadIdx.x;
    if (b < NB) {
        __shared__ int hu[ND], hm[ND];
        for (int t = tid; t < ND; t += 1024) { hu[t] = 0; hm[t] = 0; }
        __syncthreads();
        int e0 = b * chunk, e1 = min(E, e0 + chunk);
        for (int e = e0 + tid; e < e1; e += 1024) {
            atomicAdd(&hu[src[e] >> 9], 1);
            atomicAdd(&hm[dst[e] >> 7], 1);
        }
        __syncthreads();
        for (int t = tid; t < ND; t += 1024) {
            hist_u[t * NB + b] = hu[t];
            hist_m[t * NB + b] = hm[t];
        }
        return;
    }
    int p = (b - NB) * 1024 + tid;
    if (p < 4096) {
        int which = p >> 10, idx = p & 1023;
        const float* wl; const float* wr; f16x8* out;
        if (which == 0)      { wl = c1mwl; wr = c1mwr; out = wtab; }
        else if (which == 1) { wl = c1uwl; wr = c1uwr; out = wtab + 1024; }
        else if (which == 2) { wl = c2mwl; wr = c2mwr; out = wtab + 2048; }
        else                 { wl = c2uwl; wr = c2uwr; out = wtab + 3072; }
        wfrag128(wl, wr, out, idx);
    } else if (p < 5120) {
        int q = p - 4096;
        int which = q >> 9, idx = q & 511;
        wfrag64(which == 0 ? (decw1 + 64 * 64) : decw1, which == 0 ? wtab + 4096 : wtab + 4608, idx);
    } else if (p < 7168) {
        int idx = p - 5120;      // proj_w 256x64 -> 2048 fragments
        int lane_i = idx & 63, t = idx >> 6;
        int col = (t & 3) * 16 + (lane_i & 15);
        int krow = (t >> 2) * 32 + ((lane_i >> 4) << 3);
        f16x8 v;
        #pragma unroll
        for (int j = 0; j < 8; ++j)
            v[j] = (_Float16)projw[(size_t)(krow + j) * 64 + col];
        (wtab + 5120)[t * 64 + lane_i] = v;
    } else {
        int i = p - 7168;
        if (i < un4) {
            float4 v = ((const float4*)uemb)[i];
            ((f16x4*)user16)[i] = f16x4{(_Float16)v.x, (_Float16)v.y, (_Float16)v.z, (_Float16)v.w};
        }
    }
}

// ---------------- both-side scan chain (grid-split) ----------------
__global__ void k_scan_local2(const int* __restrict__ hist, int* __restrict__ scanned,
                              int* __restrict__ bsums, int NF) {
    __shared__ int s[1024];
    int side = blockIdx.x >> 6, b = blockIdx.x & 63;
    const int* in = hist + side * NF;
    int* outp = scanned + side * NF;
    int base = b * 1024;
    for (int t = threadIdx.x; t < 1024; t += 256) s[t] = in[base + t];
    __syncthreads();
    for (int d = 1; d < 1024; d <<= 1) {
        int vals[4];
        for (int j = 0; j < 4; ++j) {
            int t = threadIdx.x + j * 256;
            vals[j] = (t >= d) ? s[t - d] : 0;
        }
        __syncthreads();
        for (int j = 0; j < 4; ++j) {
            int t = threadIdx.x + j * 256;
            s[t] += vals[j];
        }
        __syncthreads();
    }
    for (int t = threadIdx.x; t < 1024; t += 256) outp[base + t] = s[t];
    if (threadIdx.x == 0) bsums[side * 64 + b] = s[1023];
}

__global__ void k_scan_carry2(int* bsums) {
    __shared__ int s[64];
    int* bs = bsums + blockIdx.x * 64;
    int t = threadIdx.x;
    if (t < 64) s[t] = bs[t];
    __syncthreads();
    if (t < 64) {
        int v = s[t];
        #pragma unroll
        for (int o = 1; o < 64; o <<= 1) {
            int u = __shfl_up(v, o, 64);
            if (t >= o) v += u;
        }
        bs[t] = v;
    }
}

__global__ void k_scan_off2(const int* __restrict__ scanned, const int* __restrict__ bsums,
                            int* __restrict__ off_m, int* __restrict__ off_u, int NF) {
    int idx = blockIdx.x * 256 + threadIdx.x;
    int side = idx / (NF + 1), i = idx - side * (NF + 1);
    if (side > 1) return;
    const int* sc = scanned + side * NF;
    const int* bs = bsums + side * 64;
    int v = 0;
    if (i > 0) {
        int j = i - 1, b = j >> 10;
        v = sc[j] + (b > 0 ? bs[b - 1] : 0);
    }
    (side ? off_u : off_m)[i] = v;
}

// ---------------- both-side scatter (no global atomics, 1024 thr) ----------------
__global__ __launch_bounds__(1024) void k_scatter2(const int* __restrict__ src, const int* __restrict__ dst,
                                                   const int* __restrict__ off_flat_m, const int* __restrict__ off_flat_u,
                                                   int2* __restrict__ tmp_m, int2* __restrict__ tmp_u,
                                                   int E, int chunk) {
    __shared__ int cnt[ND];
    int side = blockIdx.x >= NB;
    int b = blockIdx.x & (NB - 1);
    const int* key = side ? src : dst;
    const int* val = side ? dst : src;
    const int* off = side ? off_flat_u : off_flat_m;
    int2* tmp = side ? tmp_u : tmp_m;
    int shift = side ? 9 : 7;
    for (int t = threadIdx.x; t < ND; t += 1024) cnt[t] = 0;
    __syncthreads();
    int e0 = b * chunk, e1 = min(E, e0 + chunk);
    for (int e = e0 + threadIdx.x; e < e1; e += 1024) {
        int k = key[e];
        int d = k >> shift;
        int r = atomicAdd(&cnt[d], 1);
        tmp[off[d * NB + b] + r] = make_int2(k, val[e]);
    }
}

// ---------------- both-side per-bucket counting sort (1024 thr) ----------------
__global__ __launch_bounds__(1024) void k_bucket2(const int2* __restrict__ tmp_m, const int2* __restrict__ tmp_u,
                                                  const int* __restrict__ off_flat_m, const int* __restrict__ off_flat_u,
                                                  int* __restrict__ adj_m, int* __restrict__ adj_u,
                                                  int* __restrict__ offn_m, int* __restrict__ offn_u,
                                                  int E, int M, int U) {
    __shared__ int cnt[512];
    int side = blockIdx.x >= ND;
    int d = blockIdx.x & (ND - 1);
    const int2* tmp = side ? tmp_u : tmp_m;
    const int* off_flat = side ? off_flat_u : off_flat_m;
    int* adj = side ? adj_u : adj_m;
    int* off_node = side ? offn_u : offn_m;
    int NN = side ? U : M;
    int shift = side ? 9 : 7;
    int width = 1 << shift;
    int bstart = off_flat[d * NB];
    int bend   = off_flat[(d + 1 == ND) ? (ND * NB) : ((d + 1) * NB)];
    for (int t = threadIdx.x; t < width; t += 1024) cnt[t] = 0;
    __syncthreads();
    int bsz = bend - bstart;
    for (int i = threadIdx.x; i < bsz; i += 1024)
        atomicAdd(&cnt[tmp[bstart + i].x & (width - 1)], 1);
    __syncthreads();
    int lane = threadIdx.x;
    if (lane < 64) {
        int EPL = width >> 6;          // 2 (movie) or 8 (user)
        int vals[8];
        int tot = 0;
        #pragma unroll
        for (int j = 0; j < 8; ++j) {
            vals[j] = (j < EPL) ? cnt[lane * EPL + j] : 0;
            tot += vals[j];
        }
        int inc = tot;
        #pragma unroll
        for (int o = 1; o < 64; o <<= 1) {
            int tsh = __shfl_up(inc, o, 64);
            if (lane >= o) inc += tsh;
        }
        int ex = inc - tot;
        #pragma unroll
        for (int j = 0; j < 8; ++j) {
            if (j < EPL) { cnt[lane * EPL + j] = ex; ex += vals[j]; }
        }
    }
    __syncthreads();
    int base_node = d << shift;
    for (int t = threadIdx.x; t < width; t += 1024) {
        int node = base_node + t;
        if (node < NN) off_node[node] = bstart + cnt[t];
    }
    if (d == 0 && threadIdx.x == 0) off_node[NN] = E;
    __syncthreads();
    for (int i = threadIdx.x; i < bsz; i += 1024) {
        int2 e = tmp[bstart + i];
        int r = atomicAdd(&cnt[e.x & (width - 1)], 1);
        adj[bstart + r] = e.y;
    }
}

// ---------------- movie projection via MFMA: f16 out only ----------------
__global__ __launch_bounds__(256, 4) void k_proj_mfma(const float* __restrict__ mx,
                                                      const f16x8* __restrict__ wfrag,
                                                      const float* __restrict__ b,
                                                      _Float16* __restrict__ out16, int M) {
    __shared__ f16x8 wf[32 * 64];
    const int tid = threadIdx.x;
    for (int t = tid; t < 2048; t += 256)
        ((float4*)wf)[t] = ((const float4*)wfrag)[t];
    __syncthreads();
    const int w = tid >> 6, lane = tid & 63;
    const int g = lane >> 4, c15 = lane & 15;
    const int w16 = w * 16;
    float blv[4];
    #pragma unroll
    for (int nt = 0; nt < 4; ++nt) blv[nt] = b[nt * 16 + c15];
    f16x8 afz;
    #pragma unroll
    for (int j = 0; j < 8; ++j) afz[j] = (_Float16)0.f;
    for (int n0 = blockIdx.x * 64; n0 < M; n0 += gridDim.x * 64) {
        int na = n0 + w16 + c15;
        f32x4 acc[4];
        #pragma unroll
        for (int nt = 0; nt < 4; ++nt) acc[nt] = f32x4{0.f, 0.f, 0.f, 0.f};
        #pragma unroll
        for (int kt = 0; kt < 8; ++kt) {
            f16x8 af = afz;
            if (na < M) {
                const float* row = mx + (size_t)na * 256 + kt * 32 + g * 8;
                float4 a = *(const float4*)row, bq = *(const float4*)(row + 4);
                af = f16x8{(_Float16)a.x, (_Float16)a.y, (_Float16)a.z, (_Float16)a.w,
                           (_Float16)bq.x, (_Float16)bq.y, (_Float16)bq.z, (_Float16)bq.w};
            }
            #pragma unroll
            for (int nt = 0; nt < 4; ++nt)
                acc[nt] = __builtin_amdgcn_mfma_f32_16x16x32_f16(af, wf[(kt * 4 + nt) * 64 + lane],
                                                                 acc[nt], 0, 0, 0);
        }
        #pragma unroll
        for (int nt = 0; nt < 4; ++nt) {
            #pragma unroll
            for (int r = 0; r < 4; ++r) {
                int n = n0 + w16 + g * 4 + r;
                if (n < M)
                    out16[(size_t)n * 64 + nt * 16 + c15] = (_Float16)fmaxf(acc[nt][r] + blv[nt], 0.f);
            }
        }
    }
}

// ---------------- gather-side segment mean (round-15 proven form, single side) ----------------
__global__ __launch_bounds__(256) void k_agg_h(const _Float16* __restrict__ x,
                                               const int* __restrict__ adj,
                                               const int* __restrict__ off,
                                               _Float16* __restrict__ out16, int N) {
    int node = blockIdx.x * 4 + (threadIdx.x >> 6);
    if (node >= N) return;
    int lane = threadIdx.x & 63;
    int g = lane >> 3;
    int i = lane & 7;
    int s0 = off[node], s1 = off[node + 1];
    f16x8 acc0, acc1;
    #pragma unroll
    for (int j = 0; j < 8; ++j) { acc0[j] = (_Float16)0.f; acc1[j] = (_Float16)0.f; }
    int e = s0 + g;
    for (; e + 8 < s1; e += 16) {
        f16x8 v = ((const f16x8*)x)[(size_t)adj[e] * 8 + i];
        f16x8 w = ((const f16x8*)x)[(size_t)adj[e + 8] * 8 + i];
        acc0 += v;
        acc1 += w;
    }
    if (e < s1) {
        f16x8 v = ((const f16x8*)x)[(size_t)adj[e] * 8 + i];
        acc0 += v;
    }
    float f[8];
    #pragma unroll
    for (int j = 0; j < 8; ++j) f[j] = (float)acc0[j] + (float)acc1[j];
    #pragma unroll
    for (int o = 8; o <= 32; o <<= 1) {
        #pragma unroll
        for (int j = 0; j < 8; ++j) f[j] += __shfl_xor(f[j], o, 64);
    }
    int deg = s1 - s0;
    float scale = (deg > 0) ? 1.0f / (float)deg : 0.f;
    if (g == 0) {
        f16x8 r;
        #pragma unroll
        for (int j = 0; j < 8; ++j) r[j] = (_Float16)(f[j] * scale);
        ((f16x8*)out16)[(size_t)node * 8 + i] = r;
    }
}

// ---------------- merged layer-1 transform via MFMA; all-f16 ----------------
__global__ __launch_bounds__(256, 6) void k_trans1x(const _Float16* __restrict__ mean_m,
                                                    const _Float16* __restrict__ self_m,
                                                    const f16x8* __restrict__ wf_m,
                                                    const float* __restrict__ bl_m,
                                                    _Float16* __restrict__ res_m, int M,
                                                    const _Float16* __restrict__ mean_u,
                                                    const _Float16* __restrict__ self_u,
                                                    const f16x8* __restrict__ wf_u,
                                                    const float* __restrict__ bl_u,
                                                    _Float16* __restrict__ res_u, int U, int GM) {
    __shared__ f16x8 wf[16 * 64];
    int bid = blockIdx.x;
    int side = bid >= GM;
    const _Float16* mean16 = side ? mean_u : mean_m;
    const _Float16* self16 = side ? self_u : self_m;
    const f16x8* wfrag = side ? wf_u : wf_m;
    const float* bl = side ? bl_u : bl_m;
    _Float16* res16 = side ? res_u : res_m;
    int N = side ? U : M;
    int n0 = (side ? bid - GM : bid) * 64;
    const int tid = threadIdx.x;
    for (int t = tid; t < 1024; t += 256)
        ((float4*)wf)[t] = ((const float4*)wfrag)[t];
    __syncthreads();
    const int w = tid >> 6, lane = tid & 63;
    const int g = lane >> 4, c15 = lane & 15;
    const int w16 = w * 16;
    float blv[4];
    #pragma unroll
    for (int nt = 0; nt < 4; ++nt) blv[nt] = bl[nt * 16 + c15];
    f16x8 afz;
    #pragma unroll
    for (int j = 0; j < 8; ++j) afz[j] = (_Float16)0.f;
    int na = n0 + w16 + c15;
    f16x8 af[4] = {afz, afz, afz, afz};
    if (na < N) {
        const _Float16* mrow = mean16 + (size_t)na * 64 + g * 8;
        const _Float16* srow = self16 + (size_t)na * 64 + g * 8;
        af[0] = *(const f16x8*)mrow;
        af[1] = *(const f16x8*)(mrow + 32);
        af[2] = *(const f16x8*)srow;
        af[3] = *(const f16x8*)(srow + 32);
    }
    f32x4 acc[4];
    #pragma unroll
    for (int nt = 0; nt < 4; ++nt) acc[nt] = f32x4{0.f, 0.f, 0.f, 0.f};
    #pragma unroll
    for (int kt = 0; kt < 4; ++kt) {
        #pragma unroll
        for (int nt = 0; nt < 4; ++nt)
            acc[nt] = __builtin_amdgcn_mfma_f32_16x16x32_f16(af[kt], wf[(kt * 4 + nt) * 64 + lane],
                                                             acc[nt], 0, 0, 0);
    }
    #pragma unroll
    for (int nt = 0; nt < 4; ++nt) {
        #pragma unroll
        for (int r = 0; r < 4; ++r) {
            int n = n0 + w16 + g * 4 + r;
            if (n < N) {
                size_t o = (size_t)n * 64 + nt * 16 + c15;
                res16[o] = (_Float16)((float)self16[o] + fmaxf(acc[nt][r] + blv[nt], 0.f));
            }
        }
    }
}

// ---------------- merged layer-2 transform + l2norm + decoder half-projection ----------------
__global__ __launch_bounds__(256, 4) void k_trans2x(const _Float16* __restrict__ mean_m,
                                                    const _Float16* __restrict__ res_m,
                                                    const f16x8* __restrict__ wf_m,
                                                    const f16x8* __restrict__ wd_m,
                                                    const float* __restrict__ bl_m,
                                                    _Float16* __restrict__ out_m, int M,
                                                    const _Float16* __restrict__ mean_u,
                                                    const _Float16* __restrict__ res_u,
                                                    const f16x8* __restrict__ wf_u,
                                                    const f16x8* __restrict__ wd_u,
                                                    const float* __restrict__ bl_u,
                                                    _Float16* __restrict__ out_u, int U, int GM) {
    __shared__ f16x8 wf[16 * 64];
    __shared__ f16x8 wf2[8 * 64];
    __shared__ _Float16 xs2[64][72];
    int bid = blockIdx.x;
    int side = bid >= GM;
    const _Float16* mean16 = side ? mean_u : mean_m;
    const _Float16* res16 = side ? res_u : res_m;
    const f16x8* wfrag = side ? wf_u : wf_m;
    const f16x8* wdfrag = side ? wd_u : wd_m;
    const float* bl = side ? bl_u : bl_m;
    _Float16* outA16 = side ? out_u : out_m;
    int N = side ? U : M;
    int n0 = (side ? bid - GM : bid) * 64;
    const int tid = threadIdx.x;
    for (int t = tid; t < 1024; t += 256)
        ((float4*)wf)[t] = ((const float4*)wfrag)[t];
    for (int t = tid; t < 512; t += 256)
        ((float4*)wf2)[t] = ((const float4*)wdfrag)[t];
    __syncthreads();
    const int w = tid >> 6, lane = tid & 63;
    const int g = lane >> 4, c15 = lane & 15;
    const int w16 = w * 16;
    float blv[4];
    #pragma unroll
    for (int nt = 0; nt < 4; ++nt) blv[nt] = bl[nt * 16 + c15];
    f16x8 afz;
    #pragma unroll
    for (int j = 0; j < 8; ++j) afz[j] = (_Float16)0.f;
    int na = n0 + w16 + c15;
    f16x8 af[4] = {afz, afz, afz, afz};
    if (na < N) {
        const _Float16* mrow = mean16 + (size_t)na * 64 + g * 8;
        const _Float16* rrow = res16 + (size_t)na * 64 + g * 8;
        af[0] = *(const f16x8*)mrow;
        af[1] = *(const f16x8*)(mrow + 32);
        af[2] = *(const f16x8*)rrow;
        af[3] = *(const f16x8*)(rrow + 32);
    }
    f32x4 acc[4];
    #pragma unroll
    for (int nt = 0; nt < 4; ++nt) acc[nt] = f32x4{0.f, 0.f, 0.f, 0.f};
    #pragma unroll
    for (int kt = 0; kt < 4; ++kt) {
        #pragma unroll
        for (int nt = 0; nt < 4; ++nt)
            acc[nt] = __builtin_amdgcn_mfma_f32_16x16x32_f16(af[kt], wf[(kt * 4 + nt) * 64 + lane],
                                                             acc[nt], 0, 0, 0);
    }
    float u2[4][4];
    #pragma unroll
    for (int nt = 0; nt < 4; ++nt)
        #pragma unroll
        for (int r = 0; r < 4; ++r)
            u2[nt][r] = acc[nt][r] + blv[nt];
    float sc[4];
    #pragma unroll
    for (int r = 0; r < 4; ++r) {
        float q = u2[0][r] * u2[0][r] + u2[1][r] * u2[1][r]
                + u2[2][r] * u2[2][r] + u2[3][r] * u2[3][r];
        q += __shfl_xor(q, 1, 64);
        q += __shfl_xor(q, 2, 64);
        q += __shfl_xor(q, 4, 64);
        q += __shfl_xor(q, 8, 64);
        sc[r] = 1.f / fmaxf(sqrtf(q), 1e-12f);
    }
    #pragma unroll
    for (int nt = 0; nt < 4; ++nt)
        #pragma unroll
        for (int r = 0; r < 4; ++r)
            xs2[w16 + g * 4 + r][nt * 16 + c15] = (_Float16)(u2[nt][r] * sc[r]);
    f32x4 acc2[4];
    #pragma unroll
    for (int nt = 0; nt < 4; ++nt) acc2[nt] = f32x4{0.f, 0.f, 0.f, 0.f};
    #pragma unroll
    for (int kt = 0; kt < 2; ++kt) {
        f16x8 af2 = *(const f16x8*)&xs2[w16 + c15][kt * 32 + (g << 3)];
        #pragma unroll
        for (int nt = 0; nt < 4; ++nt)
            acc2[nt] = __builtin_amdgcn_mfma_f32_16x16x32_f16(af2, wf2[(kt * 4 + nt) * 64 + lane],
                                                              acc2[nt], 0, 0, 0);
    }
    #pragma unroll
    for (int nt = 0; nt < 4; ++nt) {
        #pragma unroll
        for (int r = 0; r < 4; ++r) {
            int n = n0 + w16 + g * 4 + r;
            if (n < N)
                outA16[(size_t)n * 64 + nt * 16 + c15] = (_Float16)acc2[nt][r];
        }
    }
}

// ---------------- decoder on f16 tables (8 edges/wave) ----------------
__global__ __launch_bounds__(256) void k_dec_h(const _Float16* __restrict__ A,
                                               const _Float16* __restrict__ B,
                                               const int* __restrict__ ls,
                                               const int* __restrict__ ld,
                                               const float* __restrict__ b1,
                                               const float* __restrict__ w2,
                                               const float* __restrict__ b2,
                                               float* __restrict__ out, int EL) {
    int lane = threadIdx.x & 63;
    int g = lane >> 3, i = lane & 7;
    int e = blockIdx.x * 32 + (threadIdx.x >> 6) * 8 + g;
    if (e >= EL) return;
    int u = ls[e], m = ld[e];
    f16x8 av = ((const f16x8*)A)[(size_t)u * 8 + i];
    f16x8 bv = ((const f16x8*)B)[(size_t)m * 8 + i];
    float4 b1a = ((const float4*)b1)[i * 2], b1b = ((const float4*)b1)[i * 2 + 1];
    float4 w2a = ((const float4*)w2)[i * 2], w2b = ((const float4*)w2)[i * 2 + 1];
    float p = 0.f;
    #pragma unroll
    for (int j = 0; j < 4; ++j) {
        p += fmaxf((float)av[j] + (float)bv[j] + (&b1a.x)[j], 0.f) * (&w2a.x)[j];
        p += fmaxf((float)av[j + 4] + (float)bv[j + 4] + (&b1b.x)[j], 0.f) * (&w2b.x)[j];
    }
    p += __shfl_xor(p, 1, 64);
    p += __shfl_xor(p, 2, 64);
    p += __shfl_xor(p, 4, 64);
    if (i == 0) out[e] = p + b2[0];
}

extern "C" void kernel_launch(void* const* d_in, const int* in_sizes, int n_in,
                              void* d_out, int out_size, void* d_ws, size_t ws_size,
                              hipStream_t stream) {
    const float* movie_x  = (const float*)d_in[0];
    const float* user_emb = (const float*)d_in[1];
    const float* proj_w   = (const float*)d_in[2];
    const float* proj_b   = (const float*)d_in[3];
    const float* c1_um_wl = (const float*)d_in[4];
    const float* c1_um_bl = (const float*)d_in[5];
    const float* c1_um_wr = (const float*)d_in[6];
    const float* c1_mu_wl = (const float*)d_in[7];
    const float* c1_mu_bl = (const float*)d_in[8];
    const float* c1_mu_wr = (const float*)d_in[9];
    const float* c2_um_wl = (const float*)d_in[10];
    const float* c2_um_bl = (const float*)d_in[11];
    const float* c2_um_wr = (const float*)d_in[12];
    const float* c2_mu_wl = (const float*)d_in[13];
    const float* c2_mu_bl = (const float*)d_in[14];
    const float* c2_mu_wr = (const float*)d_in[15];
    const float* dec_w1   = (const float*)d_in[16];
    const float* dec_b1   = (const float*)d_in[17];
    const float* dec_w2   = (const float*)d_in[18];
    const float* dec_b2   = (const float*)d_in[19];
    const int* edge_src = (const int*)d_in[20];
    const int* edge_dst = (const int*)d_in[21];
    const int* lbl_src  = (const int*)d_in[22];
    const int* lbl_dst  = (const int*)d_in[23];

    const int M  = in_sizes[0] / 256;
    const int U  = in_sizes[1] / 64;
    const int E  = in_sizes[20];
    const int EL = in_sizes[22];
    float* out = (float*)d_out;

    char* ws = (char*)d_ws;
    size_t off = 0;
    auto alloc = [&](size_t bytes) -> void* {
        off = (off + 255) & ~(size_t)255;
        void* p = ws + off;
        off += bytes;
        return p;
    };
    const int NF = ND * NB;
    int* hist       = (int*)alloc((size_t)2 * NF * 4);   // [hist_m | hist_u]
    int* scanned    = (int*)alloc((size_t)2 * NF * 4);
    int* bsums      = (int*)alloc(512);
    int* off_flat_m = (int*)alloc((size_t)(NF + 1) * 4);
    int* off_flat_u = (int*)alloc((size_t)(NF + 1) * 4);
    int2* tmp_m     = (int2*)alloc((size_t)E * 8);
    int2* tmp_u     = (int2*)alloc((size_t)E * 8);
    int* off_u  = (int*)alloc((size_t)(U + 1) * 4);
    int* off_m  = (int*)alloc((size_t)(M + 1) * 4);
    int* adj_u  = (int*)alloc((size_t)E * 4);
    int* adj_m  = (int*)alloc((size_t)E * 4);
    f16x8* wtab = (f16x8*)alloc(7168 * 16);
    _Float16* movie16  = (_Float16*)alloc((size_t)M * 64 * 2);
    _Float16* user16   = (_Float16*)alloc((size_t)U * 64 * 2);
    _Float16* mean16_m = (_Float16*)alloc((size_t)M * 64 * 2);
    _Float16* mean16_u = (_Float16*)alloc((size_t)U * 64 * 2);
    _Float16* m_res16  = (_Float16*)alloc((size_t)M * 64 * 2);
    _Float16* u_res16  = (_Float16*)alloc((size_t)U * 64 * 2);
    _Float16* A16 = (_Float16*)alloc((size_t)U * 64 * 2);
    _Float16* B16 = (_Float16*)alloc((size_t)M * 64 * 2);

    f16x8* wf1m = wtab;
    f16x8* wf1u = wtab + 1024;
    f16x8* wf2m = wtab + 2048;
    f16x8* wf2u = wtab + 3072;
    f16x8* wdm  = wtab + 4096;
    f16x8* wdu  = wtab + 4608;
    f16x8* wpj  = wtab + 5120;

    int* hist_m = hist;
    int* hist_u = hist + NF;

    auto cdiv = [](int a, int b) { return (a + b - 1) / b; };
    const int chunk = cdiv(E, NB);

    hipMemsetAsync(hist, 0, (size_t)2 * NF * 4, stream);
    // fused: histograms + weight prep + user16 convert
    k_init<<<NB + cdiv(7168 + U * 16, 1024), 1024, 0, stream>>>(
        edge_src, edge_dst, hist_u, hist_m, E, chunk,
        c1_um_wl, c1_um_wr, c1_mu_wl, c1_mu_wr,
        c2_um_wl, c2_um_wr, c2_mu_wl, c2_mu_wr,
        dec_w1, proj_w, user_emb, wtab, user16, U * 16);

    k_scan_local2<<<128, 256, 0, stream>>>(hist, scanned, bsums, NF);
    k_scan_carry2<<<2, 64, 0, stream>>>(bsums);
    k_scan_off2<<<cdiv(2 * (NF + 1), 256), 256, 0, stream>>>(scanned, bsums, off_flat_m, off_flat_u, NF);
    k_scatter2<<<2 * NB, 1024, 0, stream>>>(edge_src, edge_dst, off_flat_m, off_flat_u, tmp_m, tmp_u, E, chunk);
    k_bucket2<<<2 * ND, 1024, 0, stream>>>(tmp_m, tmp_u, off_flat_m, off_flat_u,
                                           adj_m, adj_u, off_m, off_u, E, M, U);

    int gm = cdiv(M, 64), gu = cdiv(U, 64);
    int gm4 = cdiv(M, 4), gu4 = cdiv(U, 4);

    k_proj_mfma<<<min(gm, 2048), 256, 0, stream>>>(movie_x, wpj, proj_b, movie16, M);

    // layer 1: sequential per-side aggs (L2 isolation), merged transform
    k_agg_h<<<gm4, 256, 0, stream>>>(user16, adj_m, off_m, mean16_m, M);
    k_agg_h<<<gu4, 256, 0, stream>>>(movie16, adj_u, off_u, mean16_u, U);
    k_trans1x<<<gm + gu, 256, 0, stream>>>(mean16_m, movie16, wf1m, c1_um_bl, m_res16, M,
                                           mean16_u, user16, wf1u, c1_mu_bl, u_res16, U, gm);

    // layer 2
    k_agg_h<<<gm4, 256, 0, stream>>>(u_res16, adj_m, off_m, mean16_m, M);
    k_agg_h<<<gu4, 256, 0, stream>>>(m_res16, adj_u, off_u, mean16_u, U);
    k_trans2x<<<gm + gu, 256, 0, stream>>>(mean16_m, m_res16, wf2m, wdm, c2_um_bl, B16, M,
                                           mean16_u, u_res16, wf2u, wdu, c2_mu_bl, A16, U, gm);

    // decoder
    k_dec_h<<<cdiv(EL, 32), 256, 0, stream>>>(A16, B16, lbl_src, lbl_dst,
                                              dec_b1, dec_w2, dec_b2, out, EL);
}

// Round 22
// 275.066 us; speedup vs baseline: 1.0336x; 1.0336x over previous
//
#include <hip/hip_runtime.h>

#define NB 256   // edge chunks for hist/scatter passes
#define ND 256   // digit buckets

typedef _Float16 f16x8 __attribute__((ext_vector_type(8)));
typedef _Float16 f16x4 __attribute__((ext_vector_type(4)));
typedef float f32x4 __attribute__((ext_vector_type(4)));

__device__ inline void wfrag128(const float* wl, const float* wr, f16x8* out, int idx) {
    int lane_i = idx & 63, t = idx >> 6;
    int col = (t & 3) * 16 + (lane_i & 15);
    int krow = (t >> 2) * 32 + ((lane_i >> 4) << 3);
    f16x8 v;
    #pragma unroll
    for (int j = 0; j < 8; ++j) {
        int k = krow + j;
        const float* W = (k < 64) ? (wl + (size_t)k * 64) : (wr + (size_t)(k - 64) * 64);
        v[j] = (_Float16)W[col];
    }
    out[t * 64 + lane_i] = v;
}
__device__ inline void wfrag64(const float* wd, f16x8* out, int idx) {
    int lane_i = idx & 63, t = idx >> 6;
    int col = (t & 3) * 16 + (lane_i & 15);
    int krow = (t >> 2) * 32 + ((lane_i >> 4) << 3);
    f16x8 v;
    #pragma unroll
    for (int j = 0; j < 8; ++j)
        v[j] = (_Float16)wd[(size_t)(krow + j) * 64 + col];
    out[t * 64 + lane_i] = v;
}

// ---------------- fused start-of-frame: histograms + all weight prep + user16 convert ----------------
__global__ __launch_bounds__(1024) void k_init(const int* __restrict__ src, const int* __restrict__ dst,
                                               int* __restrict__ hist_u, int* __restrict__ hist_m,
                                               int E, int chunk,
                                               const float* __restrict__ c1mwl, const float* __restrict__ c1mwr,
                                               const float* __restrict__ c1uwl, const float* __restrict__ c1uwr,
                                               const float* __restrict__ c2mwl, const float* __restrict__ c2mwr,
                                               const float* __restrict__ c2uwl, const float* __restrict__ c2uwr,
                                               const float* __restrict__ decw1, const float* __restrict__ projw,
                                               const float* __restrict__ uemb,
                                               f16x8* __restrict__ wtab, _Float16* __restrict__ user16, int un4) {
    int b = blockIdx.x, tid = threadIdx.x;
    if (b < NB) {
        __shared__ int hu[ND], hm[ND];
        for (int t = tid; t < ND; t += 1024) { hu[t] = 0; hm[t] = 0; }
        __syncthreads();
        int e0 = b * chunk, e1 = min(E, e0 + chunk);
        for (int e = e0 + tid; e < e1; e += 1024) {
            atomicAdd(&hu[src[e] >> 9], 1);
            atomicAdd(&hm[dst[e] >> 7], 1);
        }
        __syncthreads();
        for (int t = tid; t < ND; t += 1024) {
            hist_u[t * NB + b] = hu[t];
            hist_m[t * NB + b] = hm[t];
        }
        return;
    }
    int p = (b - NB) * 1024 + tid;
    if (p < 4096) {
        int which = p >> 10, idx = p & 1023;
        const float* wl; const float* wr; f16x8* out;
        if (which == 0)      { wl = c1mwl; wr = c1mwr; out = wtab; }
        else if (which == 1) { wl = c1uwl; wr = c1uwr; out = wtab + 1024; }
        else if (which == 2) { wl = c2mwl; wr = c2mwr; out = wtab + 2048; }
        else                 { wl = c2uwl; wr = c2uwr; out = wtab + 3072; }
        wfrag128(wl, wr, out, idx);
    } else if (p < 5120) {
        int q = p - 4096;
        int which = q >> 9, idx = q & 511;
        wfrag64(which == 0 ? (decw1 + 64 * 64) : decw1, which == 0 ? wtab + 4096 : wtab + 4608, idx);
    } else if (p < 7168) {
        int idx = p - 5120;      // proj_w 256x64 -> 2048 fragments
        int lane_i = idx & 63, t = idx >> 6;
        int col = (t & 3) * 16 + (lane_i & 15);
        int krow = (t >> 2) * 32 + ((lane_i >> 4) << 3);
        f16x8 v;
        #pragma unroll
        for (int j = 0; j < 8; ++j)
            v[j] = (_Float16)projw[(size_t)(krow + j) * 64 + col];
        (wtab + 5120)[t * 64 + lane_i] = v;
    } else {
        int i = p - 7168;
        if (i < un4) {
            float4 v = ((const float4*)uemb)[i];
            ((f16x4*)user16)[i] = f16x4{(_Float16)v.x, (_Float16)v.y, (_Float16)v.z, (_Float16)v.w};
        }
    }
}

// ---------------- both-side scan chain (grid-split) ----------------
__global__ void k_scan_local2(const int* __restrict__ hist, int* __restrict__ scanned,
                              int* __restrict__ bsums, int NF) {
    __shared__ int s[1024];
    int side = blockIdx.x >> 6, b = blockIdx.x & 63;
    const int* in = hist + side * NF;
    int* outp = scanned + side * NF;
    int base = b * 1024;
    for (int t = threadIdx.x; t < 1024; t += 256) s[t] = in[base + t];
    __syncthreads();
    for (int d = 1; d < 1024; d <<= 1) {
        int vals[4];
        for (int j = 0; j < 4; ++j) {
            int t = threadIdx.x + j * 256;
            vals[j] = (t >= d) ? s[t - d] : 0;
        }
        __syncthreads();
        for (int j = 0; j < 4; ++j) {
            int t = threadIdx.x + j * 256;
            s[t] += vals[j];
        }
        __syncthreads();
    }
    for (int t = threadIdx.x; t < 1024; t += 256) outp[base + t] = s[t];
    if (threadIdx.x == 0) bsums[side * 64 + b] = s[1023];
}

__global__ void k_scan_carry2(int* bsums) {
    __shared__ int s[64];
    int* bs = bsums + blockIdx.x * 64;
    int t = threadIdx.x;
    if (t < 64) s[t] = bs[t];
    __syncthreads();
    if (t < 64) {
        int v = s[t];
        #pragma unroll
        for (int o = 1; o < 64; o <<= 1) {
            int u = __shfl_up(v, o, 64);
            if (t >= o) v += u;
        }
        bs[t] = v;
    }
}

__global__ void k_scan_off2(const int* __restrict__ scanned, const int* __restrict__ bsums,
                            int* __restrict__ off_m, int* __restrict__ off_u, int NF) {
    int idx = blockIdx.x * 256 + threadIdx.x;
    int side = idx / (NF + 1), i = idx - side * (NF + 1);
    if (side > 1) return;
    const int* sc = scanned + side * NF;
    const int* bs = bsums + side * 64;
    int v = 0;
    if (i > 0) {
        int j = i - 1, b = j >> 10;
        v = sc[j] + (b > 0 ? bs[b - 1] : 0);
    }
    (side ? off_u : off_m)[i] = v;
}

// ---------------- both-side scatter (no global atomics, 1024 thr) ----------------
__global__ __launch_bounds__(1024) void k_scatter2(const int* __restrict__ src, const int* __restrict__ dst,
                                                   const int* __restrict__ off_flat_m, const int* __restrict__ off_flat_u,
                                                   int2* __restrict__ tmp_m, int2* __restrict__ tmp_u,
                                                   int E, int chunk) {
    __shared__ int cnt[ND];
    int side = blockIdx.x >= NB;
    int b = blockIdx.x & (NB - 1);
    const int* key = side ? src : dst;
    const int* val = side ? dst : src;
    const int* off = side ? off_flat_u : off_flat_m;
    int2* tmp = side ? tmp_u : tmp_m;
    int shift = side ? 9 : 7;
    for (int t = threadIdx.x; t < ND; t += 1024) cnt[t] = 0;
    __syncthreads();
    int e0 = b * chunk, e1 = min(E, e0 + chunk);
    for (int e = e0 + threadIdx.x; e < e1; e += 1024) {
        int k = key[e];
        int d = k >> shift;
        int r = atomicAdd(&cnt[d], 1);
        tmp[off[d * NB + b] + r] = make_int2(k, val[e]);
    }
}

// ---------------- both-side per-bucket counting sort (1024 thr) ----------------
__global__ __launch_bounds__(1024) void k_bucket2(const int2* __restrict__ tmp_m, const int2* __restrict__ tmp_u,
                                                  const int* __restrict__ off_flat_m, const int* __restrict__ off_flat_u,
                                                  int* __restrict__ adj_m, int* __restrict__ adj_u,
                                                  int* __restrict__ offn_m, int* __restrict__ offn_u,
                                                  int E, int M, int U) {
    __shared__ int cnt[512];
    int side = blockIdx.x >= ND;
    int d = blockIdx.x & (ND - 1);
    const int2* tmp = side ? tmp_u : tmp_m;
    const int* off_flat = side ? off_flat_u : off_flat_m;
    int* adj = side ? adj_u : adj_m;
    int* off_node = side ? offn_u : offn_m;
    int NN = side ? U : M;
    int shift = side ? 9 : 7;
    int width = 1 << shift;
    int bstart = off_flat[d * NB];
    int bend   = off_flat[(d + 1 == ND) ? (ND * NB) : ((d + 1) * NB)];
    for (int t = threadIdx.x; t < width; t += 1024) cnt[t] = 0;
    __syncthreads();
    int bsz = bend - bstart;
    for (int i = threadIdx.x; i < bsz; i += 1024)
        atomicAdd(&cnt[tmp[bstart + i].x & (width - 1)], 1);
    __syncthreads();
    int lane = threadIdx.x;
    if (lane < 64) {
        int EPL = width >> 6;          // 2 (movie) or 8 (user)
        int vals[8];
        int tot = 0;
        #pragma unroll
        for (int j = 0; j < 8; ++j) {
            vals[j] = (j < EPL) ? cnt[lane * EPL + j] : 0;
            tot += vals[j];
        }
        int inc = tot;
        #pragma unroll
        for (int o = 1; o < 64; o <<= 1) {
            int tsh = __shfl_up(inc, o, 64);
            if (lane >= o) inc += tsh;
        }
        int ex = inc - tot;
        #pragma unroll
        for (int j = 0; j < 8; ++j) {
            if (j < EPL) { cnt[lane * EPL + j] = ex; ex += vals[j]; }
        }
    }
    __syncthreads();
    int base_node = d << shift;
    for (int t = threadIdx.x; t < width; t += 1024) {
        int node = base_node + t;
        if (node < NN) off_node[node] = bstart + cnt[t];
    }
    if (d == 0 && threadIdx.x == 0) off_node[NN] = E;
    __syncthreads();
    for (int i = threadIdx.x; i < bsz; i += 1024) {
        int2 e = tmp[bstart + i];
        int r = atomicAdd(&cnt[e.x & (width - 1)], 1);
        adj[bstart + r] = e.y;
    }
}

// ---------------- movie projection via MFMA: f16 out only ----------------
__global__ __launch_bounds__(256, 4) void k_proj_mfma(const float* __restrict__ mx,
                                                      const f16x8* __restrict__ wfrag,
                                                      const float* __restrict__ b,
                                                      _Float16* __restrict__ out16, int M) {
    __shared__ f16x8 wf[32 * 64];
    const int tid = threadIdx.x;
    for (int t = tid; t < 2048; t += 256)
        ((float4*)wf)[t] = ((const float4*)wfrag)[t];
    __syncthreads();
    const int w = tid >> 6, lane = tid & 63;
    const int g = lane >> 4, c15 = lane & 15;
    const int w16 = w * 16;
    float blv[4];
    #pragma unroll
    for (int nt = 0; nt < 4; ++nt) blv[nt] = b[nt * 16 + c15];
    f16x8 afz;
    #pragma unroll
    for (int j = 0; j < 8; ++j) afz[j] = (_Float16)0.f;
    for (int n0 = blockIdx.x * 64; n0 < M; n0 += gridDim.x * 64) {
        int na = n0 + w16 + c15;
        f32x4 acc[4];
        #pragma unroll
        for (int nt = 0; nt < 4; ++nt) acc[nt] = f32x4{0.f, 0.f, 0.f, 0.f};
        #pragma unroll
        for (int kt = 0; kt < 8; ++kt) {
            f16x8 af = afz;
            if (na < M) {
                const float* row = mx + (size_t)na * 256 + kt * 32 + g * 8;
                float4 a = *(const float4*)row, bq = *(const float4*)(row + 4);
                af = f16x8{(_Float16)a.x, (_Float16)a.y, (_Float16)a.z, (_Float16)a.w,
                           (_Float16)bq.x, (_Float16)bq.y, (_Float16)bq.z, (_Float16)bq.w};
            }
            #pragma unroll
            for (int nt = 0; nt < 4; ++nt)
                acc[nt] = __builtin_amdgcn_mfma_f32_16x16x32_f16(af, wf[(kt * 4 + nt) * 64 + lane],
                                                                 acc[nt], 0, 0, 0);
        }
        #pragma unroll
        for (int nt = 0; nt < 4; ++nt) {
            #pragma unroll
            for (int r = 0; r < 4; ++r) {
                int n = n0 + w16 + g * 4 + r;
                if (n < M)
                    out16[(size_t)n * 64 + nt * 16 + c15] = (_Float16)fmaxf(acc[nt][r] + blv[nt], 0.f);
            }
        }
    }
}

// ---------------- merged both-side gather segment mean (round-20 proven faster) ----------------
__global__ __launch_bounds__(256) void k_agg2(const _Float16* __restrict__ xm,
                                              const int* __restrict__ adj_m, const int* __restrict__ off_m,
                                              _Float16* __restrict__ out_m, int M,
                                              const _Float16* __restrict__ xu,
                                              const int* __restrict__ adj_u, const int* __restrict__ off_u,
                                              _Float16* __restrict__ out_u, int U, int gm4) {
    int bid = blockIdx.x;
    int side = bid >= gm4;
    const _Float16* x = side ? xu : xm;
    const int* adj = side ? adj_u : adj_m;
    const int* off = side ? off_u : off_m;
    _Float16* out16 = side ? out_u : out_m;
    int N = side ? U : M;
    int node = (side ? bid - gm4 : bid) * 4 + (threadIdx.x >> 6);
    if (node >= N) return;
    int lane = threadIdx.x & 63;
    int g = lane >> 3;
    int i = lane & 7;
    int s0 = off[node], s1 = off[node + 1];
    f16x8 acc0, acc1;
    #pragma unroll
    for (int j = 0; j < 8; ++j) { acc0[j] = (_Float16)0.f; acc1[j] = (_Float16)0.f; }
    int e = s0 + g;
    for (; e + 8 < s1; e += 16) {
        f16x8 v = ((const f16x8*)x)[(size_t)adj[e] * 8 + i];
        f16x8 w = ((const f16x8*)x)[(size_t)adj[e + 8] * 8 + i];
        acc0 += v;
        acc1 += w;
    }
    if (e < s1) {
        f16x8 v = ((const f16x8*)x)[(size_t)adj[e] * 8 + i];
        acc0 += v;
    }
    float f[8];
    #pragma unroll
    for (int j = 0; j < 8; ++j) f[j] = (float)acc0[j] + (float)acc1[j];
    #pragma unroll
    for (int o = 8; o <= 32; o <<= 1) {
        #pragma unroll
        for (int j = 0; j < 8; ++j) f[j] += __shfl_xor(f[j], o, 64);
    }
    int deg = s1 - s0;
    float scale = (deg > 0) ? 1.0f / (float)deg : 0.f;
    if (g == 0) {
        f16x8 r;
        #pragma unroll
        for (int j = 0; j < 8; ++j) r[j] = (_Float16)(f[j] * scale);
        ((f16x8*)out16)[(size_t)node * 8 + i] = r;
    }
}

// ---------------- merged layer-1 transform via MFMA; all-f16 ----------------
__global__ __launch_bounds__(256, 6) void k_trans1x(const _Float16* __restrict__ mean_m,
                                                    const _Float16* __restrict__ self_m,
                                                    const f16x8* __restrict__ wf_m,
                                                    const float* __restrict__ bl_m,
                                                    _Float16* __restrict__ res_m, int M,
                                                    const _Float16* __restrict__ mean_u,
                                                    const _Float16* __restrict__ self_u,
                                                    const f16x8* __restrict__ wf_u,
                                                    const float* __restrict__ bl_u,
                                                    _Float16* __restrict__ res_u, int U, int GM) {
    __shared__ f16x8 wf[16 * 64];
    int bid = blockIdx.x;
    int side = bid >= GM;
    const _Float16* mean16 = side ? mean_u : mean_m;
    const _Float16* self16 = side ? self_u : self_m;
    const f16x8* wfrag = side ? wf_u : wf_m;
    const float* bl = side ? bl_u : bl_m;
    _Float16* res16 = side ? res_u : res_m;
    int N = side ? U : M;
    int n0 = (side ? bid - GM : bid) * 64;
    const int tid = threadIdx.x;
    for (int t = tid; t < 1024; t += 256)
        ((float4*)wf)[t] = ((const float4*)wfrag)[t];
    __syncthreads();
    const int w = tid >> 6, lane = tid & 63;
    const int g = lane >> 4, c15 = lane & 15;
    const int w16 = w * 16;
    float blv[4];
    #pragma unroll
    for (int nt = 0; nt < 4; ++nt) blv[nt] = bl[nt * 16 + c15];
    f16x8 afz;
    #pragma unroll
    for (int j = 0; j < 8; ++j) afz[j] = (_Float16)0.f;
    int na = n0 + w16 + c15;
    f16x8 af[4] = {afz, afz, afz, afz};
    if (na < N) {
        const _Float16* mrow = mean16 + (size_t)na * 64 + g * 8;
        const _Float16* srow = self16 + (size_t)na * 64 + g * 8;
        af[0] = *(const f16x8*)mrow;
        af[1] = *(const f16x8*)(mrow + 32);
        af[2] = *(const f16x8*)srow;
        af[3] = *(const f16x8*)(srow + 32);
    }
    f32x4 acc[4];
    #pragma unroll
    for (int nt = 0; nt < 4; ++nt) acc[nt] = f32x4{0.f, 0.f, 0.f, 0.f};
    #pragma unroll
    for (int kt = 0; kt < 4; ++kt) {
        #pragma unroll
        for (int nt = 0; nt < 4; ++nt)
            acc[nt] = __builtin_amdgcn_mfma_f32_16x16x32_f16(af[kt], wf[(kt * 4 + nt) * 64 + lane],
                                                             acc[nt], 0, 0, 0);
    }
    #pragma unroll
    for (int nt = 0; nt < 4; ++nt) {
        #pragma unroll
        for (int r = 0; r < 4; ++r) {
            int n = n0 + w16 + g * 4 + r;
            if (n < N) {
                size_t o = (size_t)n * 64 + nt * 16 + c15;
                res16[o] = (_Float16)((float)self16[o] + fmaxf(acc[nt][r] + blv[nt], 0.f));
            }
        }
    }
}

// ---------------- merged layer-2 transform + l2norm + decoder half-projection ----------------
__global__ __launch_bounds__(256, 4) void k_trans2x(const _Float16* __restrict__ mean_m,
                                                    const _Float16* __restrict__ res_m,
                                                    const f16x8* __restrict__ wf_m,
                                                    const f16x8* __restrict__ wd_m,
                                                    const float* __restrict__ bl_m,
                                                    _Float16* __restrict__ out_m, int M,
                                                    const _Float16* __restrict__ mean_u,
                                                    const _Float16* __restrict__ res_u,
                                                    const f16x8* __restrict__ wf_u,
                                                    const f16x8* __restrict__ wd_u,
                                                    const float* __restrict__ bl_u,
                                                    _Float16* __restrict__ out_u, int U, int GM) {
    __shared__ f16x8 wf[16 * 64];
    __shared__ f16x8 wf2[8 * 64];
    __shared__ _Float16 xs2[64][72];
    int bid = blockIdx.x;
    int side = bid >= GM;
    const _Float16* mean16 = side ? mean_u : mean_m;
    const _Float16* res16 = side ? res_u : res_m;
    const f16x8* wfrag = side ? wf_u : wf_m;
    const f16x8* wdfrag = side ? wd_u : wd_m;
    const float* bl = side ? bl_u : bl_m;
    _Float16* outA16 = side ? out_u : out_m;
    int N = side ? U : M;
    int n0 = (side ? bid - GM : bid) * 64;
    const int tid = threadIdx.x;
    for (int t = tid; t < 1024; t += 256)
        ((float4*)wf)[t] = ((const float4*)wfrag)[t];
    for (int t = tid; t < 512; t += 256)
        ((float4*)wf2)[t] = ((const float4*)wdfrag)[t];
    __syncthreads();
    const int w = tid >> 6, lane = tid & 63;
    const int g = lane >> 4, c15 = lane & 15;
    const int w16 = w * 16;
    float blv[4];
    #pragma unroll
    for (int nt = 0; nt < 4; ++nt) blv[nt] = bl[nt * 16 + c15];
    f16x8 afz;
    #pragma unroll
    for (int j = 0; j < 8; ++j) afz[j] = (_Float16)0.f;
    int na = n0 + w16 + c15;
    f16x8 af[4] = {afz, afz, afz, afz};
    if (na < N) {
        const _Float16* mrow = mean16 + (size_t)na * 64 + g * 8;
        const _Float16* rrow = res16 + (size_t)na * 64 + g * 8;
        af[0] = *(const f16x8*)mrow;
        af[1] = *(const f16x8*)(mrow + 32);
        af[2] = *(const f16x8*)rrow;
        af[3] = *(const f16x8*)(rrow + 32);
    }
    f32x4 acc[4];
    #pragma unroll
    for (int nt = 0; nt < 4; ++nt) acc[nt] = f32x4{0.f, 0.f, 0.f, 0.f};
    #pragma unroll
    for (int kt = 0; kt < 4; ++kt) {
        #pragma unroll
        for (int nt = 0; nt < 4; ++nt)
            acc[nt] = __builtin_amdgcn_mfma_f32_16x16x32_f16(af[kt], wf[(kt * 4 + nt) * 64 + lane],
                                                             acc[nt], 0, 0, 0);
    }
    float u2[4][4];
    #pragma unroll
    for (int nt = 0; nt < 4; ++nt)
        #pragma unroll
        for (int r = 0; r < 4; ++r)
            u2[nt][r] = acc[nt][r] + blv[nt];
    float sc[4];
    #pragma unroll
    for (int r = 0; r < 4; ++r) {
        float q = u2[0][r] * u2[0][r] + u2[1][r] * u2[1][r]
                + u2[2][r] * u2[2][r] + u2[3][r] * u2[3][r];
        q += __shfl_xor(q, 1, 64);
        q += __shfl_xor(q, 2, 64);
        q += __shfl_xor(q, 4, 64);
        q += __shfl_xor(q, 8, 64);
        sc[r] = 1.f / fmaxf(sqrtf(q), 1e-12f);
    }
    #pragma unroll
    for (int nt = 0; nt < 4; ++nt)
        #pragma unroll
        for (int r = 0; r < 4; ++r)
            xs2[w16 + g * 4 + r][nt * 16 + c15] = (_Float16)(u2[nt][r] * sc[r]);
    f32x4 acc2[4];
    #pragma unroll
    for (int nt = 0; nt < 4; ++nt) acc2[nt] = f32x4{0.f, 0.f, 0.f, 0.f};
    #pragma unroll
    for (int kt = 0; kt < 2; ++kt) {
        f16x8 af2 = *(const f16x8*)&xs2[w16 + c15][kt * 32 + (g << 3)];
        #pragma unroll
        for (int nt = 0; nt < 4; ++nt)
            acc2[nt] = __builtin_amdgcn_mfma_f32_16x16x32_f16(af2, wf2[(kt * 4 + nt) * 64 + lane],
                                                              acc2[nt], 0, 0, 0);
    }
    #pragma unroll
    for (int nt = 0; nt < 4; ++nt) {
        #pragma unroll
        for (int r = 0; r < 4; ++r) {
            int n = n0 + w16 + g * 4 + r;
            if (n < N)
                outA16[(size_t)n * 64 + nt * 16 + c15] = (_Float16)acc2[nt][r];
        }
    }
}

// ---------------- decoder on f16 tables (8 edges/wave) ----------------
__global__ __launch_bounds__(256) void k_dec_h(const _Float16* __restrict__ A,
                                               const _Float16* __restrict__ B,
                                               const int* __restrict__ ls,
                                               const int* __restrict__ ld,
                                               const float* __restrict__ b1,
                                               const float* __restrict__ w2,
                                               const float* __restrict__ b2,
                                               float* __restrict__ out, int EL) {
    int lane = threadIdx.x & 63;
    int g = lane >> 3, i = lane & 7;
    int e = blockIdx.x * 32 + (threadIdx.x >> 6) * 8 + g;
    if (e >= EL) return;
    int u = ls[e], m = ld[e];
    f16x8 av = ((const f16x8*)A)[(size_t)u * 8 + i];
    f16x8 bv = ((const f16x8*)B)[(size_t)m * 8 + i];
    float4 b1a = ((const float4*)b1)[i * 2], b1b = ((const float4*)b1)[i * 2 + 1];
    float4 w2a = ((const float4*)w2)[i * 2], w2b = ((const float4*)w2)[i * 2 + 1];
    float p = 0.f;
    #pragma unroll
    for (int j = 0; j < 4; ++j) {
        p += fmaxf((float)av[j] + (float)bv[j] + (&b1a.x)[j], 0.f) * (&w2a.x)[j];
        p += fmaxf((float)av[j + 4] + (float)bv[j + 4] + (&b1b.x)[j], 0.f) * (&w2b.x)[j];
    }
    p += __shfl_xor(p, 1, 64);
    p += __shfl_xor(p, 2, 64);
    p += __shfl_xor(p, 4, 64);
    if (i == 0) out[e] = p + b2[0];
}

extern "C" void kernel_launch(void* const* d_in, const int* in_sizes, int n_in,
                              void* d_out, int out_size, void* d_ws, size_t ws_size,
                              hipStream_t stream) {
    const float* movie_x  = (const float*)d_in[0];
    const float* user_emb = (const float*)d_in[1];
    const float* proj_w   = (const float*)d_in[2];
    const float* proj_b   = (const float*)d_in[3];
    const float* c1_um_wl = (const float*)d_in[4];
    const float* c1_um_bl = (const float*)d_in[5];
    const float* c1_um_wr = (const float*)d_in[6];
    const float* c1_mu_wl = (const float*)d_in[7];
    const float* c1_mu_bl = (const float*)d_in[8];
    const float* c1_mu_wr = (const float*)d_in[9];
    const float* c2_um_wl = (const float*)d_in[10];
    const float* c2_um_bl = (const float*)d_in[11];
    const float* c2_um_wr = (const float*)d_in[12];
    const float* c2_mu_wl = (const float*)d_in[13];
    const float* c2_mu_bl = (const float*)d_in[14];
    const float* c2_mu_wr = (const float*)d_in[15];
    const float* dec_w1   = (const float*)d_in[16];
    const float* dec_b1   = (const float*)d_in[17];
    const float* dec_w2   = (const float*)d_in[18];
    const float* dec_b2   = (const float*)d_in[19];
    const int* edge_src = (const int*)d_in[20];
    const int* edge_dst = (const int*)d_in[21];
    const int* lbl_src  = (const int*)d_in[22];
    const int* lbl_dst  = (const int*)d_in[23];

    const int M  = in_sizes[0] / 256;
    const int U  = in_sizes[1] / 64;
    const int E  = in_sizes[20];
    const int EL = in_sizes[22];
    float* out = (float*)d_out;

    char* ws = (char*)d_ws;
    size_t off = 0;
    auto alloc = [&](size_t bytes) -> void* {
        off = (off + 255) & ~(size_t)255;
        void* p = ws + off;
        off += bytes;
        return p;
    };
    const int NF = ND * NB;
    int* hist       = (int*)alloc((size_t)2 * NF * 4);   // [hist_m | hist_u]
    int* scanned    = (int*)alloc((size_t)2 * NF * 4);
    int* bsums      = (int*)alloc(512);
    int* off_flat_m = (int*)alloc((size_t)(NF + 1) * 4);
    int* off_flat_u = (int*)alloc((size_t)(NF + 1) * 4);
    int2* tmp_m     = (int2*)alloc((size_t)E * 8);
    int2* tmp_u     = (int2*)alloc((size_t)E * 8);
    int* off_u  = (int*)alloc((size_t)(U + 1) * 4);
    int* off_m  = (int*)alloc((size_t)(M + 1) * 4);
    int* adj_u  = (int*)alloc((size_t)E * 4);
    int* adj_m  = (int*)alloc((size_t)E * 4);
    f16x8* wtab = (f16x8*)alloc(7168 * 16);
    _Float16* movie16  = (_Float16*)alloc((size_t)M * 64 * 2);
    _Float16* user16   = (_Float16*)alloc((size_t)U * 64 * 2);
    _Float16* mean16_m = (_Float16*)alloc((size_t)M * 64 * 2);
    _Float16* mean16_u = (_Float16*)alloc((size_t)U * 64 * 2);
    _Float16* m_res16  = (_Float16*)alloc((size_t)M * 64 * 2);
    _Float16* u_res16  = (_Float16*)alloc((size_t)U * 64 * 2);
    _Float16* A16 = (_Float16*)alloc((size_t)U * 64 * 2);
    _Float16* B16 = (_Float16*)alloc((size_t)M * 64 * 2);

    f16x8* wf1m = wtab;
    f16x8* wf1u = wtab + 1024;
    f16x8* wf2m = wtab + 2048;
    f16x8* wf2u = wtab + 3072;
    f16x8* wdm  = wtab + 4096;
    f16x8* wdu  = wtab + 4608;
    f16x8* wpj  = wtab + 5120;

    int* hist_m = hist;
    int* hist_u = hist + NF;

    auto cdiv = [](int a, int b) { return (a + b - 1) / b; };
    const int chunk = cdiv(E, NB);

    hipMemsetAsync(hist, 0, (size_t)2 * NF * 4, stream);
    // fused: histograms + weight prep + user16 convert
    k_init<<<NB + cdiv(7168 + U * 16, 1024), 1024, 0, stream>>>(
        edge_src, edge_dst, hist_u, hist_m, E, chunk,
        c1_um_wl, c1_um_wr, c1_mu_wl, c1_mu_wr,
        c2_um_wl, c2_um_wr, c2_mu_wl, c2_mu_wr,
        dec_w1, proj_w, user_emb, wtab, user16, U * 16);

    k_scan_local2<<<128, 256, 0, stream>>>(hist, scanned, bsums, NF);
    k_scan_carry2<<<2, 64, 0, stream>>>(bsums);
    k_scan_off2<<<cdiv(2 * (NF + 1), 256), 256, 0, stream>>>(scanned, bsums, off_flat_m, off_flat_u, NF);
    k_scatter2<<<2 * NB, 1024, 0, stream>>>(edge_src, edge_dst, off_flat_m, off_flat_u, tmp_m, tmp_u, E, chunk);
    k_bucket2<<<2 * ND, 1024, 0, stream>>>(tmp_m, tmp_u, off_flat_m, off_flat_u,
                                           adj_m, adj_u, off_m, off_u, E, M, U);

    int gm = cdiv(M, 64), gu = cdiv(U, 64);
    int gm4 = cdiv(M, 4), gu4 = cdiv(U, 4);

    k_proj_mfma<<<min(gm, 2048), 256, 0, stream>>>(movie_x, wpj, proj_b, movie16, M);

    // layer 1 (merged agg — round-20 A/B showed overlap beats L2 isolation)
    k_agg2<<<gm4 + gu4, 256, 0, stream>>>(user16, adj_m, off_m, mean16_m, M,
                                          movie16, adj_u, off_u, mean16_u, U, gm4);
    k_trans1x<<<gm + gu, 256, 0, stream>>>(mean16_m, movie16, wf1m, c1_um_bl, m_res16, M,
                                           mean16_u, user16, wf1u, c1_mu_bl, u_res16, U, gm);

    // layer 2
    k_agg2<<<gm4 + gu4, 256, 0, stream>>>(u_res16, adj_m, off_m, mean16_m, M,
                                          m_res16, adj_u, off_u, mean16_u, U, gm4);
    k_trans2x<<<gm + gu, 256, 0, stream>>>(mean16_m, m_res16, wf2m, wdm, c2_um_bl, B16, M,
                                           mean16_u, u_res16, wf2u, wdu, c2_mu_bl, A16, U, gm);

    // decoder
    k_dec_h<<<cdiv(EL, 32), 256, 0, stream>>>(A16, B16, lbl_src, lbl_dst,
                                              dec_b1, dec_w2, dec_b2, out, EL);
}

// Round 23
// 257.661 us; speedup vs baseline: 1.1034x; 1.0675x over previous
//
#include <hip/hip_runtime.h>

#define NB 256   // edge chunks for hist/scatter passes
#define ND 256   // digit buckets

typedef _Float16 f16x8 __attribute__((ext_vector_type(8)));
typedef _Float16 f16x4 __attribute__((ext_vector_type(4)));
typedef float f32x4 __attribute__((ext_vector_type(4)));

__device__ inline void wfrag128(const float* wl, const float* wr, f16x8* out, int idx) {
    int lane_i = idx & 63, t = idx >> 6;
    int col = (t & 3) * 16 + (lane_i & 15);
    int krow = (t >> 2) * 32 + ((lane_i >> 4) << 3);
    f16x8 v;
    #pragma unroll
    for (int j = 0; j < 8; ++j) {
        int k = krow + j;
        const float* W = (k < 64) ? (wl + (size_t)k * 64) : (wr + (size_t)(k - 64) * 64);
        v[j] = (_Float16)W[col];
    }
    out[t * 64 + lane_i] = v;
}
__device__ inline void wfrag64(const float* wd, f16x8* out, int idx) {
    int lane_i = idx & 63, t = idx >> 6;
    int col = (t & 3) * 16 + (lane_i & 15);
    int krow = (t >> 2) * 32 + ((lane_i >> 4) << 3);
    f16x8 v;
    #pragma unroll
    for (int j = 0; j < 8; ++j)
        v[j] = (_Float16)wd[(size_t)(krow + j) * 64 + col];
    out[t * 64 + lane_i] = v;
}

// ---------------- fused start-of-frame: histograms + all weight prep + user16 convert ----------------
__global__ __launch_bounds__(1024) void k_init(const int* __restrict__ src, const int* __restrict__ dst,
                                               int* __restrict__ hist_u, int* __restrict__ hist_m,
                                               int E, int chunk,
                                               const float* __restrict__ c1mwl, const float* __restrict__ c1mwr,
                                               const float* __restrict__ c1uwl, const float* __restrict__ c1uwr,
                                               const float* __restrict__ c2mwl, const float* __restrict__ c2mwr,
                                               const float* __restrict__ c2uwl, const float* __restrict__ c2uwr,
                                               const float* __restrict__ decw1, const float* __restrict__ projw,
                                               const float* __restrict__ uemb,
                                               f16x8* __restrict__ wtab, _Float16* __restrict__ user16, int un4) {
    int b = blockIdx.x, tid = threadIdx.x;
    if (b < NB) {
        __shared__ int hu[ND], hm[ND];
        for (int t = tid; t < ND; t += 1024) { hu[t] = 0; hm[t] = 0; }
        __syncthreads();
        int e0 = b * chunk, e1 = min(E, e0 + chunk);
        for (int e = e0 + tid; e < e1; e += 1024) {
            atomicAdd(&hu[src[e] >> 9], 1);
            atomicAdd(&hm[dst[e] >> 7], 1);
        }
        __syncthreads();
        for (int t = tid; t < ND; t += 1024) {
            hist_u[t * NB + b] = hu[t];
            hist_m[t * NB + b] = hm[t];
        }
        return;
    }
    int p = (b - NB) * 1024 + tid;
    if (p < 4096) {
        int which = p >> 10, idx = p & 1023;
        const float* wl; const float* wr; f16x8* out;
        if (which == 0)      { wl = c1mwl; wr = c1mwr; out = wtab; }
        else if (which == 1) { wl = c1uwl; wr = c1uwr; out = wtab + 1024; }
        else if (which == 2) { wl = c2mwl; wr = c2mwr; out = wtab + 2048; }
        else                 { wl = c2uwl; wr = c2uwr; out = wtab + 3072; }
        wfrag128(wl, wr, out, idx);
    } else if (p < 5120) {
        int q = p - 4096;
        int which = q >> 9, idx = q & 511;
        wfrag64(which == 0 ? (decw1 + 64 * 64) : decw1, which == 0 ? wtab + 4096 : wtab + 4608, idx);
    } else if (p < 7168) {
        int idx = p - 5120;      // proj_w 256x64 -> 2048 fragments
        int lane_i = idx & 63, t = idx >> 6;
        int col = (t & 3) * 16 + (lane_i & 15);
        int krow = (t >> 2) * 32 + ((lane_i >> 4) << 3);
        f16x8 v;
        #pragma unroll
        for (int j = 0; j < 8; ++j)
            v[j] = (_Float16)projw[(size_t)(krow + j) * 64 + col];
        (wtab + 5120)[t * 64 + lane_i] = v;
    } else {
        int i = p - 7168;
        if (i < un4) {
            float4 v = ((const float4*)uemb)[i];
            ((f16x4*)user16)[i] = f16x4{(_Float16)v.x, (_Float16)v.y, (_Float16)v.z, (_Float16)v.w};
        }
    }
}

// ---------------- both-side scan chain (grid-split) ----------------
__global__ void k_scan_local2(const int* __restrict__ hist, int* __restrict__ scanned,
                              int* __restrict__ bsums, int NF) {
    __shared__ int s[1024];
    int side = blockIdx.x >> 6, b = blockIdx.x & 63;
    const int* in = hist + side * NF;
    int* outp = scanned + side * NF;
    int base = b * 1024;
    for (int t = threadIdx.x; t < 1024; t += 256) s[t] = in[base + t];
    __syncthreads();
    for (int d = 1; d < 1024; d <<= 1) {
        int vals[4];
        for (int j = 0; j < 4; ++j) {
            int t = threadIdx.x + j * 256;
            vals[j] = (t >= d) ? s[t - d] : 0;
        }
        __syncthreads();
        for (int j = 0; j < 4; ++j) {
            int t = threadIdx.x + j * 256;
            s[t] += vals[j];
        }
        __syncthreads();
    }
    for (int t = threadIdx.x; t < 1024; t += 256) outp[base + t] = s[t];
    if (threadIdx.x == 0) bsums[side * 64 + b] = s[1023];
}

__global__ void k_scan_carry2(int* bsums) {
    __shared__ int s[64];
    int* bs = bsums + blockIdx.x * 64;
    int t = threadIdx.x;
    if (t < 64) s[t] = bs[t];
    __syncthreads();
    if (t < 64) {
        int v = s[t];
        #pragma unroll
        for (int o = 1; o < 64; o <<= 1) {
            int u = __shfl_up(v, o, 64);
            if (t >= o) v += u;
        }
        bs[t] = v;
    }
}

__global__ void k_scan_off2(const int* __restrict__ scanned, const int* __restrict__ bsums,
                            int* __restrict__ off_m, int* __restrict__ off_u, int NF) {
    int idx = blockIdx.x * 256 + threadIdx.x;
    int side = idx / (NF + 1), i = idx - side * (NF + 1);
    if (side > 1) return;
    const int* sc = scanned + side * NF;
    const int* bs = bsums + side * 64;
    int v = 0;
    if (i > 0) {
        int j = i - 1, b = j >> 10;
        v = sc[j] + (b > 0 ? bs[b - 1] : 0);
    }
    (side ? off_u : off_m)[i] = v;
}

// ---------------- both-side scatter with PACKED tmp (lowbits<<17 | val) ----------------
__global__ __launch_bounds__(1024) void k_scatter2(const int* __restrict__ src, const int* __restrict__ dst,
                                                   const int* __restrict__ off_flat_m, const int* __restrict__ off_flat_u,
                                                   int* __restrict__ tmp_m, int* __restrict__ tmp_u,
                                                   int E, int chunk) {
    __shared__ int cnt[ND];
    int side = blockIdx.x >= NB;
    int b = blockIdx.x & (NB - 1);
    const int* key = side ? src : dst;
    const int* val = side ? dst : src;
    const int* off = side ? off_flat_u : off_flat_m;
    int* tmp = side ? tmp_u : tmp_m;
    int shift = side ? 9 : 7;
    int wmask = (1 << shift) - 1;
    for (int t = threadIdx.x; t < ND; t += 1024) cnt[t] = 0;
    __syncthreads();
    int e0 = b * chunk, e1 = min(E, e0 + chunk);
    for (int e = e0 + threadIdx.x; e < e1; e += 1024) {
        int k = key[e];
        int d = k >> shift;
        int r = atomicAdd(&cnt[d], 1);
        tmp[off[d * NB + b] + r] = ((k & wmask) << 17) | val[e];
    }
}

// ---------------- fused: both-side bucket counting sort + movie projection ----------------
__global__ __launch_bounds__(1024) void k_bucket_proj(const int* __restrict__ tmp_m, const int* __restrict__ tmp_u,
                                                      const int* __restrict__ off_flat_m, const int* __restrict__ off_flat_u,
                                                      int* __restrict__ adj_m, int* __restrict__ adj_u,
                                                      int* __restrict__ offn_m, int* __restrict__ offn_u,
                                                      int E, int M, int U,
                                                      const float* __restrict__ mx,
                                                      const f16x8* __restrict__ wpj,
                                                      const float* __restrict__ pb,
                                                      _Float16* __restrict__ movie16) {
    __shared__ int cnt[512];
    __shared__ f16x8 wf[2048];           // 32 KB (proj blocks only)
    int bid = blockIdx.x, tid = threadIdx.x;
    if (bid < 2 * ND) {
        int side = bid >= ND;
        int d = bid & (ND - 1);
        const int* tmp = side ? tmp_u : tmp_m;
        const int* off_flat = side ? off_flat_u : off_flat_m;
        int* adj = side ? adj_u : adj_m;
        int* off_node = side ? offn_u : offn_m;
        int NN = side ? U : M;
        int shift = side ? 9 : 7;
        int width = 1 << shift;
        int bstart = off_flat[d * NB];
        int bend   = off_flat[(d + 1 == ND) ? (ND * NB) : ((d + 1) * NB)];
        for (int t = tid; t < width; t += 1024) cnt[t] = 0;
        __syncthreads();
        int bsz = bend - bstart;
        for (int i = tid; i < bsz; i += 1024)
            atomicAdd(&cnt[tmp[bstart + i] >> 17], 1);
        __syncthreads();
        int lane = tid;
        if (lane < 64) {
            int EPL = width >> 6;
            int vals[8];
            int tot = 0;
            #pragma unroll
            for (int j = 0; j < 8; ++j) {
                vals[j] = (j < EPL) ? cnt[lane * EPL + j] : 0;
                tot += vals[j];
            }
            int inc = tot;
            #pragma unroll
            for (int o = 1; o < 64; o <<= 1) {
                int tsh = __shfl_up(inc, o, 64);
                if (lane >= o) inc += tsh;
            }
            int ex = inc - tot;
            #pragma unroll
            for (int j = 0; j < 8; ++j) {
                if (j < EPL) { cnt[lane * EPL + j] = ex; ex += vals[j]; }
            }
        }
        __syncthreads();
        int base_node = d << shift;
        for (int t = tid; t < width; t += 1024) {
            int node = base_node + t;
            if (node < NN) off_node[node] = bstart + cnt[t];
        }
        if (d == 0 && tid == 0) off_node[NN] = E;
        __syncthreads();
        for (int i = tid; i < bsz; i += 1024) {
            int v = tmp[bstart + i];
            int r = atomicAdd(&cnt[v >> 17], 1);
            adj[bstart + r] = v & 0x1FFFF;
        }
        return;
    }
    // ---- movie projection: 256-row tile, 16 waves ----
    int pt = bid - 2 * ND;
    for (int t = tid; t < 2048; t += 1024)
        ((float4*)wf)[t] = ((const float4*)wpj)[t];
    __syncthreads();
    const int w = tid >> 6, lane = tid & 63;
    const int g = lane >> 4, c15 = lane & 15;
    const int w16 = w * 16;              // 0..240
    int n0 = pt * 256;
    float blv[4];
    #pragma unroll
    for (int nt = 0; nt < 4; ++nt) blv[nt] = pb[nt * 16 + c15];
    f16x8 afz;
    #pragma unroll
    for (int j = 0; j < 8; ++j) afz[j] = (_Float16)0.f;
    int na = n0 + w16 + c15;
    f32x4 acc[4];
    #pragma unroll
    for (int nt = 0; nt < 4; ++nt) acc[nt] = f32x4{0.f, 0.f, 0.f, 0.f};
    #pragma unroll
    for (int kt = 0; kt < 8; ++kt) {
        f16x8 af = afz;
        if (na < M) {
            const float* row = mx + (size_t)na * 256 + kt * 32 + g * 8;
            float4 a = *(const float4*)row, bq = *(const float4*)(row + 4);
            af = f16x8{(_Float16)a.x, (_Float16)a.y, (_Float16)a.z, (_Float16)a.w,
                       (_Float16)bq.x, (_Float16)bq.y, (_Float16)bq.z, (_Float16)bq.w};
        }
        #pragma unroll
        for (int nt = 0; nt < 4; ++nt)
            acc[nt] = __builtin_amdgcn_mfma_f32_16x16x32_f16(af, wf[(kt * 4 + nt) * 64 + lane],
                                                             acc[nt], 0, 0, 0);
    }
    #pragma unroll
    for (int nt = 0; nt < 4; ++nt) {
        #pragma unroll
        for (int r = 0; r < 4; ++r) {
            int n = n0 + w16 + g * 4 + r;
            if (n < M)
                movie16[(size_t)n * 64 + nt * 16 + c15] = (_Float16)fmaxf(acc[nt][r] + blv[nt], 0.f);
        }
    }
}

// ---------------- merged both-side gather segment mean ----------------
__global__ __launch_bounds__(256) void k_agg2(const _Float16* __restrict__ xm,
                                              const int* __restrict__ adj_m, const int* __restrict__ off_m,
                                              _Float16* __restrict__ out_m, int M,
                                              const _Float16* __restrict__ xu,
                                              const int* __restrict__ adj_u, const int* __restrict__ off_u,
                                              _Float16* __restrict__ out_u, int U, int gm4) {
    int bid = blockIdx.x;
    int side = bid >= gm4;
    const _Float16* x = side ? xu : xm;
    const int* adj = side ? adj_u : adj_m;
    const int* off = side ? off_u : off_m;
    _Float16* out16 = side ? out_u : out_m;
    int N = side ? U : M;
    int node = (side ? bid - gm4 : bid) * 4 + (threadIdx.x >> 6);
    if (node >= N) return;
    int lane = threadIdx.x & 63;
    int g = lane >> 3;
    int i = lane & 7;
    int s0 = off[node], s1 = off[node + 1];
    f16x8 acc0, acc1;
    #pragma unroll
    for (int j = 0; j < 8; ++j) { acc0[j] = (_Float16)0.f; acc1[j] = (_Float16)0.f; }
    int e = s0 + g;
    for (; e + 8 < s1; e += 16) {
        f16x8 v = ((const f16x8*)x)[(size_t)adj[e] * 8 + i];
        f16x8 w = ((const f16x8*)x)[(size_t)adj[e + 8] * 8 + i];
        acc0 += v;
        acc1 += w;
    }
    if (e < s1) {
        f16x8 v = ((const f16x8*)x)[(size_t)adj[e] * 8 + i];
        acc0 += v;
    }
    float f[8];
    #pragma unroll
    for (int j = 0; j < 8; ++j) f[j] = (float)acc0[j] + (float)acc1[j];
    #pragma unroll
    for (int o = 8; o <= 32; o <<= 1) {
        #pragma unroll
        for (int j = 0; j < 8; ++j) f[j] += __shfl_xor(f[j], o, 64);
    }
    int deg = s1 - s0;
    float scale = (deg > 0) ? 1.0f / (float)deg : 0.f;
    if (g == 0) {
        f16x8 r;
        #pragma unroll
        for (int j = 0; j < 8; ++j) r[j] = (_Float16)(f[j] * scale);
        ((f16x8*)out16)[(size_t)node * 8 + i] = r;
    }
}

// ---------------- merged layer-1 transform via MFMA; all-f16 ----------------
__global__ __launch_bounds__(256, 6) void k_trans1x(const _Float16* __restrict__ mean_m,
                                                    const _Float16* __restrict__ self_m,
                                                    const f16x8* __restrict__ wf_m,
                                                    const float* __restrict__ bl_m,
                                                    _Float16* __restrict__ res_m, int M,
                                                    const _Float16* __restrict__ mean_u,
                                                    const _Float16* __restrict__ self_u,
                                                    const f16x8* __restrict__ wf_u,
                                                    const float* __restrict__ bl_u,
                                                    _Float16* __restrict__ res_u, int U, int GM) {
    __shared__ f16x8 wf[16 * 64];
    int bid = blockIdx.x;
    int side = bid >= GM;
    const _Float16* mean16 = side ? mean_u : mean_m;
    const _Float16* self16 = side ? self_u : self_m;
    const f16x8* wfrag = side ? wf_u : wf_m;
    const float* bl = side ? bl_u : bl_m;
    _Float16* res16 = side ? res_u : res_m;
    int N = side ? U : M;
    int n0 = (side ? bid - GM : bid) * 64;
    const int tid = threadIdx.x;
    for (int t = tid; t < 1024; t += 256)
        ((float4*)wf)[t] = ((const float4*)wfrag)[t];
    __syncthreads();
    const int w = tid >> 6, lane = tid & 63;
    const int g = lane >> 4, c15 = lane & 15;
    const int w16 = w * 16;
    float blv[4];
    #pragma unroll
    for (int nt = 0; nt < 4; ++nt) blv[nt] = bl[nt * 16 + c15];
    f16x8 afz;
    #pragma unroll
    for (int j = 0; j < 8; ++j) afz[j] = (_Float16)0.f;
    int na = n0 + w16 + c15;
    f16x8 af[4] = {afz, afz, afz, afz};
    if (na < N) {
        const _Float16* mrow = mean16 + (size_t)na * 64 + g * 8;
        const _Float16* srow = self16 + (size_t)na * 64 + g * 8;
        af[0] = *(const f16x8*)mrow;
        af[1] = *(const f16x8*)(mrow + 32);
        af[2] = *(const f16x8*)srow;
        af[3] = *(const f16x8*)(srow + 32);
    }
    f32x4 acc[4];
    #pragma unroll
    for (int nt = 0; nt < 4; ++nt) acc[nt] = f32x4{0.f, 0.f, 0.f, 0.f};
    #pragma unroll
    for (int kt = 0; kt < 4; ++kt) {
        #pragma unroll
        for (int nt = 0; nt < 4; ++nt)
            acc[nt] = __builtin_amdgcn_mfma_f32_16x16x32_f16(af[kt], wf[(kt * 4 + nt) * 64 + lane],
                                                             acc[nt], 0, 0, 0);
    }
    #pragma unroll
    for (int nt = 0; nt < 4; ++nt) {
        #pragma unroll
        for (int r = 0; r < 4; ++r) {
            int n = n0 + w16 + g * 4 + r;
            if (n < N) {
                size_t o = (size_t)n * 64 + nt * 16 + c15;
                res16[o] = (_Float16)((float)self16[o] + fmaxf(acc[nt][r] + blv[nt], 0.f));
            }
        }
    }
}

// ---------------- merged layer-2 transform + l2norm + decoder half-projection ----------------
__global__ __launch_bounds__(256, 4) void k_trans2x(const _Float16* __restrict__ mean_m,
                                                    const _Float16* __restrict__ res_m,
                                                    const f16x8* __restrict__ wf_m,
                                                    const f16x8* __restrict__ wd_m,
                                                    const float* __restrict__ bl_m,
                                                    _Float16* __restrict__ out_m, int M,
                                                    const _Float16* __restrict__ mean_u,
                                                    const _Float16* __restrict__ res_u,
                                                    const f16x8* __restrict__ wf_u,
                                                    const f16x8* __restrict__ wd_u,
                                                    const float* __restrict__ bl_u,
                                                    _Float16* __restrict__ out_u, int U, int GM) {
    __shared__ f16x8 wf[16 * 64];
    __shared__ f16x8 wf2[8 * 64];
    __shared__ _Float16 xs2[64][72];
    int bid = blockIdx.x;
    int side = bid >= GM;
    const _Float16* mean16 = side ? mean_u : mean_m;
    const _Float16* res16 = side ? res_u : res_m;
    const f16x8* wfrag = side ? wf_u : wf_m;
    const f16x8* wdfrag = side ? wd_u : wd_m;
    const float* bl = side ? bl_u : bl_m;
    _Float16* outA16 = side ? out_u : out_m;
    int N = side ? U : M;
    int n0 = (side ? bid - GM : bid) * 64;
    const int tid = threadIdx.x;
    for (int t = tid; t < 1024; t += 256)
        ((float4*)wf)[t] = ((const float4*)wfrag)[t];
    for (int t = tid; t < 512; t += 256)
        ((float4*)wf2)[t] = ((const float4*)wdfrag)[t];
    __syncthreads();
    const int w = tid >> 6, lane = tid & 63;
    const int g = lane >> 4, c15 = lane & 15;
    const int w16 = w * 16;
    float blv[4];
    #pragma unroll
    for (int nt = 0; nt < 4; ++nt) blv[nt] = bl[nt * 16 + c15];
    f16x8 afz;
    #pragma unroll
    for (int j = 0; j < 8; ++j) afz[j] = (_Float16)0.f;
    int na = n0 + w16 + c15;
    f16x8 af[4] = {afz, afz, afz, afz};
    if (na < N) {
        const _Float16* mrow = mean16 + (size_t)na * 64 + g * 8;
        const _Float16* rrow = res16 + (size_t)na * 64 + g * 8;
        af[0] = *(const f16x8*)mrow;
        af[1] = *(const f16x8*)(mrow + 32);
        af[2] = *(const f16x8*)rrow;
        af[3] = *(const f16x8*)(rrow + 32);
    }
    f32x4 acc[4];
    #pragma unroll
    for (int nt = 0; nt < 4; ++nt) acc[nt] = f32x4{0.f, 0.f, 0.f, 0.f};
    #pragma unroll
    for (int kt = 0; kt < 4; ++kt) {
        #pragma unroll
        for (int nt = 0; nt < 4; ++nt)
            acc[nt] = __builtin_amdgcn_mfma_f32_16x16x32_f16(af[kt], wf[(kt * 4 + nt) * 64 + lane],
                                                             acc[nt], 0, 0, 0);
    }
    float u2[4][4];
    #pragma unroll
    for (int nt = 0; nt < 4; ++nt)
        #pragma unroll
        for (int r = 0; r < 4; ++r)
            u2[nt][r] = acc[nt][r] + blv[nt];
    float sc[4];
    #pragma unroll
    for (int r = 0; r < 4; ++r) {
        float q = u2[0][r] * u2[0][r] + u2[1][r] * u2[1][r]
                + u2[2][r] * u2[2][r] + u2[3][r] * u2[3][r];
        q += __shfl_xor(q, 1, 64);
        q += __shfl_xor(q, 2, 64);
        q += __shfl_xor(q, 4, 64);
        q += __shfl_xor(q, 8, 64);
        sc[r] = 1.f / fmaxf(sqrtf(q), 1e-12f);
    }
    #pragma unroll
    for (int nt = 0; nt < 4; ++nt)
        #pragma unroll
        for (int r = 0; r < 4; ++r)
            xs2[w16 + g * 4 + r][nt * 16 + c15] = (_Float16)(u2[nt][r] * sc[r]);
    f32x4 acc2[4];
    #pragma unroll
    for (int nt = 0; nt < 4; ++nt) acc2[nt] = f32x4{0.f, 0.f, 0.f, 0.f};
    #pragma unroll
    for (int kt = 0; kt < 2; ++kt) {
        f16x8 af2 = *(const f16x8*)&xs2[w16 + c15][kt * 32 + (g << 3)];
        #pragma unroll
        for (int nt = 0; nt < 4; ++nt)
            acc2[nt] = __builtin_amdgcn_mfma_f32_16x16x32_f16(af2, wf2[(kt * 4 + nt) * 64 + lane],
                                                              acc2[nt], 0, 0, 0);
    }
    #pragma unroll
    for (int nt = 0; nt < 4; ++nt) {
        #pragma unroll
        for (int r = 0; r < 4; ++r) {
            int n = n0 + w16 + g * 4 + r;
            if (n < N)
                outA16[(size_t)n * 64 + nt * 16 + c15] = (_Float16)acc2[nt][r];
        }
    }
}

// ---------------- decoder on f16 tables (8 edges/wave) ----------------
__global__ __launch_bounds__(256) void k_dec_h(const _Float16* __restrict__ A,
                                               const _Float16* __restrict__ B,
                                               const int* __restrict__ ls,
                                               const int* __restrict__ ld,
                                               const float* __restrict__ b1,
                                               const float* __restrict__ w2,
                                               const float* __restrict__ b2,
                                               float* __restrict__ out, int EL) {
    int lane = threadIdx.x & 63;
    int g = lane >> 3, i = lane & 7;
    int e = blockIdx.x * 32 + (threadIdx.x >> 6) * 8 + g;
    if (e >= EL) return;
    int u = ls[e], m = ld[e];
    f16x8 av = ((const f16x8*)A)[(size_t)u * 8 + i];
    f16x8 bv = ((const f16x8*)B)[(size_t)m * 8 + i];
    float4 b1a = ((const float4*)b1)[i * 2], b1b = ((const float4*)b1)[i * 2 + 1];
    float4 w2a = ((const float4*)w2)[i * 2], w2b = ((const float4*)w2)[i * 2 + 1];
    float p = 0.f;
    #pragma unroll
    for (int j = 0; j < 4; ++j) {
        p += fmaxf((float)av[j] + (float)bv[j] + (&b1a.x)[j], 0.f) * (&w2a.x)[j];
        p += fmaxf((float)av[j + 4] + (float)bv[j + 4] + (&b1b.x)[j], 0.f) * (&w2b.x)[j];
    }
    p += __shfl_xor(p, 1, 64);
    p += __shfl_xor(p, 2, 64);
    p += __shfl_xor(p, 4, 64);
    if (i == 0) out[e] = p + b2[0];
}

extern "C" void kernel_launch(void* const* d_in, const int* in_sizes, int n_in,
                              void* d_out, int out_size, void* d_ws, size_t ws_size,
                              hipStream_t stream) {
    const float* movie_x  = (const float*)d_in[0];
    const float* user_emb = (const float*)d_in[1];
    const float* proj_w   = (const float*)d_in[2];
    const float* proj_b   = (const float*)d_in[3];
    const float* c1_um_wl = (const float*)d_in[4];
    const float* c1_um_bl = (const float*)d_in[5];
    const float* c1_um_wr = (const float*)d_in[6];
    const float* c1_mu_wl = (const float*)d_in[7];
    const float* c1_mu_bl = (const float*)d_in[8];
    const float* c1_mu_wr = (const float*)d_in[9];
    const float* c2_um_wl = (const float*)d_in[10];
    const float* c2_um_bl = (const float*)d_in[11];
    const float* c2_um_wr = (const float*)d_in[12];
    const float* c2_mu_wl = (const float*)d_in[13];
    const float* c2_mu_bl = (const float*)d_in[14];
    const float* c2_mu_wr = (const float*)d_in[15];
    const float* dec_w1   = (const float*)d_in[16];
    const float* dec_b1   = (const float*)d_in[17];
    const float* dec_w2   = (const float*)d_in[18];
    const float* dec_b2   = (const float*)d_in[19];
    const int* edge_src = (const int*)d_in[20];
    const int* edge_dst = (const int*)d_in[21];
    const int* lbl_src  = (const int*)d_in[22];
    const int* lbl_dst  = (const int*)d_in[23];

    const int M  = in_sizes[0] / 256;
    const int U  = in_sizes[1] / 64;
    const int E  = in_sizes[20];
    const int EL = in_sizes[22];
    float* out = (float*)d_out;

    char* ws = (char*)d_ws;
    size_t off = 0;
    auto alloc = [&](size_t bytes) -> void* {
        off = (off + 255) & ~(size_t)255;
        void* p = ws + off;
        off += bytes;
        return p;
    };
    const int NF = ND * NB;
    int* hist       = (int*)alloc((size_t)2 * NF * 4);   // [hist_m | hist_u]
    int* scanned    = (int*)alloc((size_t)2 * NF * 4);
    int* bsums      = (int*)alloc(512);
    int* off_flat_m = (int*)alloc((size_t)(NF + 1) * 4);
    int* off_flat_u = (int*)alloc((size_t)(NF + 1) * 4);
    int* tmp_m      = (int*)alloc((size_t)E * 4);        // PACKED
    int* tmp_u      = (int*)alloc((size_t)E * 4);        // PACKED
    int* off_u  = (int*)alloc((size_t)(U + 1) * 4);
    int* off_m  = (int*)alloc((size_t)(M + 1) * 4);
    int* adj_u  = (int*)alloc((size_t)E * 4);
    int* adj_m  = (int*)alloc((size_t)E * 4);
    f16x8* wtab = (f16x8*)alloc(7168 * 16);
    _Float16* movie16  = (_Float16*)alloc((size_t)M * 64 * 2);
    _Float16* user16   = (_Float16*)alloc((size_t)U * 64 * 2);
    _Float16* mean16_m = (_Float16*)alloc((size_t)M * 64 * 2);
    _Float16* mean16_u = (_Float16*)alloc((size_t)U * 64 * 2);
    _Float16* m_res16  = (_Float16*)alloc((size_t)M * 64 * 2);
    _Float16* u_res16  = (_Float16*)alloc((size_t)U * 64 * 2);
    _Float16* A16 = (_Float16*)alloc((size_t)U * 64 * 2);
    _Float16* B16 = (_Float16*)alloc((size_t)M * 64 * 2);

    f16x8* wf1m = wtab;
    f16x8* wf1u = wtab + 1024;
    f16x8* wf2m = wtab + 2048;
    f16x8* wf2u = wtab + 3072;
    f16x8* wdm  = wtab + 4096;
    f16x8* wdu  = wtab + 4608;
    f16x8* wpj  = wtab + 5120;

    int* hist_m = hist;
    int* hist_u = hist + NF;

    auto cdiv = [](int a, int b) { return (a + b - 1) / b; };
    const int chunk = cdiv(E, NB);

    hipMemsetAsync(hist, 0, (size_t)2 * NF * 4, stream);
    k_init<<<NB + cdiv(7168 + U * 16, 1024), 1024, 0, stream>>>(
        edge_src, edge_dst, hist_u, hist_m, E, chunk,
        c1_um_wl, c1_um_wr, c1_mu_wl, c1_mu_wr,
        c2_um_wl, c2_um_wr, c2_mu_wl, c2_mu_wr,
        dec_w1, proj_w, user_emb, wtab, user16, U * 16);

    k_scan_local2<<<128, 256, 0, stream>>>(hist, scanned, bsums, NF);
    k_scan_carry2<<<2, 64, 0, stream>>>(bsums);
    k_scan_off2<<<cdiv(2 * (NF + 1), 256), 256, 0, stream>>>(scanned, bsums, off_flat_m, off_flat_u, NF);
    k_scatter2<<<2 * NB, 1024, 0, stream>>>(edge_src, edge_dst, off_flat_m, off_flat_u, tmp_m, tmp_u, E, chunk);

    int gm = cdiv(M, 64), gu = cdiv(U, 64);
    int gm4 = cdiv(M, 4), gu4 = cdiv(U, 4);

    // bucket sort (both sides) + movie projection fused in one launch
    k_bucket_proj<<<2 * ND + cdiv(M, 256), 1024, 0, stream>>>(
        tmp_m, tmp_u, off_flat_m, off_flat_u,
        adj_m, adj_u, off_m, off_u, E, M, U,
        movie_x, wpj, proj_b, movie16);

    // layer 1
    k_agg2<<<gm4 + gu4, 256, 0, stream>>>(user16, adj_m, off_m, mean16_m, M,
                                          movie16, adj_u, off_u, mean16_u, U, gm4);
    k_trans1x<<<gm + gu, 256, 0, stream>>>(mean16_m, movie16, wf1m, c1_um_bl, m_res16, M,
                                           mean16_u, user16, wf1u, c1_mu_bl, u_res16, U, gm);

    // layer 2
    k_agg2<<<gm4 + gu4, 256, 0, stream>>>(u_res16, adj_m, off_m, mean16_m, M,
                                          m_res16, adj_u, off_u, mean16_u, U, gm4);
    k_trans2x<<<gm + gu, 256, 0, stream>>>(mean16_m, m_res16, wf2m, wdm, c2_um_bl, B16, M,
                                           mean16_u, u_res16, wf2u, wdu, c2_mu_bl, A16, U, gm);

    // decoder
    k_dec_h<<<cdiv(EL, 32), 256, 0, stream>>>(A16, B16, lbl_src, lbl_dst,
                                              dec_b1, dec_w2, dec_b2, out, EL);
}